// Round 22
// baseline (244.789 us; speedup 1.0000x reference)
//
#include <hip/hip_runtime.h>
#include <math.h>

#define M0 128
#define M1 64
#define M2 32
#define DIMN 480      // 128 + 3*64 + 5*32
#define MSGC 64
#define NBLK 3
#define RBFD 32
#define NT 512        // r-table resolution (rPI = 0.5 MB/b -> L2-resident)
#define TCHUNK 16     // t-values per k_rtab block (96 table blocks)
#define NNP0 4        // nodes per k_proj0 block
#define GNPB 2        // nodes per k_gather block (2 waves each, 256 threads)
#define PSTR 68       // mbuf plane stride (floats)
#define WROWS 224     // WoT rows: 128 + 64 + 32
#define CH 21         // edges per wave-private staged chunk (63 float4 slots)
#define FCUT 5.0f

typedef unsigned int   u32;
typedef unsigned short u16;

__device__ __forceinline__ u16 f2bf(float f) {
    u32 u = __float_as_uint(f);
    u32 r = (u + 0x7fffu + ((u >> 16) & 1u)) >> 16;
    return (u16)r;
}
__device__ __forceinline__ float bf_lo(u32 v) { return __uint_as_float(v << 16); }
__device__ __forceinline__ float bf_hi(u32 v) { return __uint_as_float(v & 0xffff0000u); }

// 48-byte dst-sorted edge record: [src,ti,fr,fc][shf1..4][shf5..8] (sh pre-scaled by fcut)
struct __align__(16) ERec {
    int   src;
    int   ti;
    float fr;
    float fc;
    float sh[8];
};

// ---------- zero counts ----------
__global__ void k_zero(int* __restrict__ p, int n) {
    int i = blockIdx.x * blockDim.x + threadIdx.x;
    if (i < n) p[i] = 0;
}

// ---------- pass 1: count edges per dst ----------
__global__ void k_count(const int* __restrict__ dst, int* __restrict__ counts, int E) {
    int e = blockIdx.x * blockDim.x + threadIdx.x;
    if (e >= E) return;
    atomicAdd(&counts[dst[e]], 1);
}

// ---------- exclusive scan, 4 elems/thread + Hillis-Steele on 1024 totals ----------
__global__ __launch_bounds__(1024) void k_scan(const int* __restrict__ counts,
                                               int* __restrict__ offs,
                                               int* __restrict__ cursor, int n) {
    __shared__ int ws[1024];
    int t = threadIdx.x;                 // n == 4096, 4 per thread
    int4 v = ((const int4*)counts)[t];
    int s0 = v.x, s1 = s0 + v.y, s2 = s1 + v.z, s3 = s2 + v.w;
    ws[t] = s3;
    __syncthreads();
    for (int d = 1; d < 1024; d <<= 1) {
        int val = (t >= d) ? ws[t - d] : 0;
        __syncthreads();
        ws[t] += val;
        __syncthreads();
    }
    int excl = (t == 0) ? 0 : ws[t - 1];
    int4 o;
    o.x = excl; o.y = excl + s0; o.z = excl + s1; o.w = excl + s2;
    ((int4*)offs)[t] = o;
    ((int4*)cursor)[t] = o;
    if (t == 1023) offs[n] = excl + s3;
}

// ---------- pass 2: edge features scattered into dst order (sh pre-scaled by fcut) ----------
__global__ void k_build(const float* __restrict__ ew, const float* __restrict__ ev,
                        const int* __restrict__ src, const int* __restrict__ dst,
                        int* __restrict__ cursor, ERec* __restrict__ rec, int E) {
    int e = blockIdx.x * blockDim.x + threadIdx.x;
    if (e >= E) return;
    float len = ew[e];
    float inv = 1.0f / fmaxf(len, 1e-8f);
    float x = ev[e * 3 + 0] * inv;
    float y = ev[e * 3 + 1] * inv;
    float z = ev[e * 3 + 2] * inv;
    const float s3 = 1.7320508075688772f, s5 = 2.23606797749979f, s15 = 3.872983346207417f;
    ERec r;
    r.src = src[e];
    float u = fminf(len, FCUT) * ((float)(NT - 1) / FCUT);
    int ti = (int)u;
    ti = min(ti, NT - 2);
    r.ti = ti;
    r.fr = u - (float)ti;
    float t = fminf(len / FCUT, 1.0f);
    float fc = 0.5f * (cosf(3.14159265358979323846f * t) + 1.0f);
    r.fc = fc;
    r.sh[0] = s3 * x * fc;
    r.sh[1] = s3 * y * fc;
    r.sh[2] = s3 * z * fc;
    r.sh[3] = s15 * x * y * fc;
    r.sh[4] = s15 * y * z * fc;
    r.sh[5] = 0.5f * s5 * (3.0f * z * z - 1.0f) * fc;
    r.sh[6] = s15 * x * z * fc;
    r.sh[7] = 0.5f * s15 * (x * x - y * y) * fc;
    int p = atomicAdd(&cursor[dst[e]], 1);
    rec[p] = r;
}

// ---------- r-table direct-pack + Wo transpose + Wp transpose (one launch) ----------
#define RTB (NBLK * (NT / TCHUNK))
__global__ __launch_bounds__(256) void k_rtab(const float* __restrict__ rW1,
                                              const float* __restrict__ rb1,
                                              const float* __restrict__ rW2,
                                              const float* __restrict__ rb2,
                                              u32* __restrict__ rPI,
                                              const float* __restrict__ Wo0,
                                              const float* __restrict__ Wo1,
                                              const float* __restrict__ Wo2,
                                              float* __restrict__ WoT,
                                              const float* __restrict__ Wp,
                                              float* __restrict__ WpT) {
    int blk = blockIdx.x;
    int tid = threadIdx.x;
    if (blk >= RTB) {
        int idx = (blk - RTB) * 256 + tid;
        const int wtot = NBLK * WROWS * 64;
        const int ptot = NBLK * 192 * 128;
        if (idx < wtot) {
            int b = idx / (WROWS * 64);
            int rem = idx - b * (WROWS * 64);
            int row = rem >> 6, c = rem & 63;
            float v;
            if (row < 128)      v = Wo0[(size_t)b * MSGC * M0 + c * M0 + row];
            else if (row < 192) v = Wo1[(size_t)b * MSGC * M1 + c * M1 + (row - 128)];
            else                v = Wo2[(size_t)b * MSGC * M2 + c * M2 + (row - 192)];
            WoT[idx] = v;
            return;
        }
        idx -= wtot;
        if (idx >= ptot) return;
        int b = idx / (192 * 128);
        int rem = idx - b * (192 * 128);
        int c = rem >> 7, k = rem & 127;
        WpT[idx] = Wp[((size_t)b * 128 + k) * 192 + c];
        return;
    }
    int b = blk / (NT / TCHUNK);
    int t0 = (blk % (NT / TCHUNK)) * TCHUNK;
    __shared__ float rbf_s[TCHUNK + 1][RBFD];
    __shared__ float hh_s[64][TCHUNK + 1];

    const float wdt = FCUT / (float)(RBFD - 1);
    for (int idx = tid; idx < (TCHUNK + 1) * RBFD; idx += 256) {
        int tt = idx >> 5, k = idx & 31;
        int te = min(t0 + tt, NT - 1);
        float len = (float)te * (FCUT / (float)(NT - 1));
        float d0 = (len - (float)k * wdt) / wdt;
        rbf_s[tt][k] = expf(-0.5f * d0 * d0);
    }
    __syncthreads();
    const float* W1 = rW1 + b * RBFD * 64;
    for (int idx = tid; idx < (TCHUNK + 1) * 64; idx += 256) {
        int tt = idx / 64, jj = idx & 63;
        float a = rb1[b * 64 + jj];
        #pragma unroll 8
        for (int k = 0; k < RBFD; ++k) a += rbf_s[tt][k] * W1[k * 64 + jj];
        hh_s[jj][tt] = a / (1.0f + expf(-a));
    }
    __syncthreads();
    if (tid < 192) {
        int c = tid;
        const float* W2 = rW2 + b * 64 * 192;
        float w2r[64];
        #pragma unroll
        for (int k = 0; k < 64; ++k) w2r[k] = W2[k * 192 + c];
        float b2 = rb2[b * 192 + c];
        int lane = c & 63, q = c >> 6;
        u32* out = rPI + ((size_t)b * NT * 64) * 4;
        float prev = 0.0f;
        for (int tt = 0; tt <= TCHUNK; ++tt) {
            float acc = b2;
            #pragma unroll
            for (int k = 0; k < 64; ++k) acc += hh_s[k][tt] * w2r[k];
            if (tt > 0) {
                int t = t0 + tt - 1;
                out[((size_t)t * 64 + lane) * 4 + q] =
                    (u32)f2bf(prev) | ((u32)f2bf(acc) << 16);
            }
            prev = acc;
        }
    }
}

// ---------- fused x-init + b=0 projection (4 nodes/block, 1024 blocks) ----------
__global__ __launch_bounds__(192) void k_proj0(const int* __restrict__ z,
                                               const float* __restrict__ mask,
                                               const float* __restrict__ zemb,
                                               const float* __restrict__ Win,
                                               const float* __restrict__ Wp,
                                               float* __restrict__ x,
                                               u16* __restrict__ PI) {
    int n0 = blockIdx.x * NNP0;
    int j = threadIdx.x;
    __shared__ float zf[NNP0][M0];
    __shared__ float xs[NNP0][M0];
    for (int idx = j; idx < NNP0 * M0; idx += 192) {
        int n = idx >> 7, c = idx & 127;
        zf[n][c] = zemb[z[n0 + n] * M0 + c];
    }
    __syncthreads();
    for (int idx = j; idx < NNP0 * M0; idx += 192) {
        int n = idx >> 7, c = idx & 127;
        float acc = 0.0f;
        for (int k = 0; k < M0; ++k) acc += zf[n][k] * Win[k * M0 + c];
        acc *= mask[n0 + n];
        xs[n][c] = acc;
        x[(size_t)(n0 + n) * DIMN + c] = acc;
    }
    for (int idx = j; idx < NNP0 * (DIMN - M0); idx += 192) {
        int n = idx / (DIMN - M0), c = idx - n * (DIMN - M0);
        x[(size_t)(n0 + n) * DIMN + M0 + c] = 0.0f;
    }
    __syncthreads();
    float acc[NNP0];
    #pragma unroll
    for (int u = 0; u < NNP0; ++u) acc[u] = 0.0f;
    for (int k = 0; k < M0; ++k) {
        float wv = Wp[k * 192 + j];
        #pragma unroll
        for (int u = 0; u < NNP0; ++u) acc[u] += xs[u][k] * wv;
    }
    int lane = j & 63, q = j >> 6;
    #pragma unroll
    for (int u = 0; u < NNP0; ++u)
        PI[((size_t)(n0 + u) * 64 + lane) * 4 + q] = f2bf(acc[u]);
}

// ---------- fused gather + Wo transform + next-block projection (+ final norm) ----------
// 256 threads = 4 waves; 2 nodes/block, 2 waves/node (contiguous edge split).
// Wave-private LDS meta staging, 2-deep register data pipeline; fused projection
// uses transposed WpT (float4 rows) -> ~4x fewer epilogue VMEM instrs.
__global__ __launch_bounds__(256, 8) void k_gather(const u16* __restrict__ PIin,
                                                   u16* __restrict__ PIout,
                                                   const u32* __restrict__ rPI,
                                                   const ERec* __restrict__ rec,
                                                   const int* __restrict__ offs,
                                                   const float* __restrict__ WoT,
                                                   const float* __restrict__ WpTn,
                                                   const float* __restrict__ res_scale, int b,
                                                   float* __restrict__ x,
                                                   const float* __restrict__ mask,
                                                   float* __restrict__ out) {
    int t = threadIdx.x;
    int w = t >> 6;          // wave 0..3
    int j = t & 63;
    int local = w >> 1;      // node within block 0..1
    int par = w & 1;         // wave half within node
    int n0 = blockIdx.x * GNPB;
    int n = n0 + local;
    int e0 = offs[n], e1 = offs[n + 1];

    float m0 = 0.0f;
    float m1a[3] = {0, 0, 0};
    float m2a[5] = {0, 0, 0, 0, 0};

    __shared__ float4 smeta[4][2][CH * 3];   // wave-private staging, double-buffered
    __shared__ float mbuf[4][9 * PSTR];      // odd slices reused as x-stash after reduce
    __shared__ float invs[GNPB][3];

    {
        int half = (e1 - e0 + 1) >> 1;
        int a    = e0 + par * half;
        int bnd  = par ? e1 : (e0 + half);
        int len  = bnd - a;
        if (len > 0) {
            const float4* RP = (const float4*)rec;
            {
                int c0 = min(CH, len);
                if (j < c0 * 3) smeta[w][0][j] = RP[(size_t)3 * a + j];
            }
            int buf = 0;
            for (int done = 0; done < len; done += CH, buf ^= 1) {
                int cnt = min(CH, len - done);
                {
                    int nd = done + CH;
                    int ncnt = min(CH, len - nd);
                    if (j < ncnt * 3) smeta[w][buf ^ 1][j] = RP[(size_t)3 * (a + nd) + j];
                }
                const float4* M = smeta[w][buf];
                int lastE = cnt - 1;
                float4 Am = M[0];
                float4 Bm = M[3 * min(1, lastE)];
                float4 Cm = M[3 * min(2, lastE)];
                float4 Dm = M[3 * min(3, lastE)];
                uint4 rA, rB, rC; uint2 pA, pB, pC;
                {
                    int s = __float_as_int(Am.x), ti = __float_as_int(Am.y);
                    rA = ((const uint4*)(rPI + ((size_t)ti << 8)))[j];
                    pA = ((const uint2*)(PIin + ((size_t)s << 8)))[j];
                }
                {
                    int s = __float_as_int(Bm.x), ti = __float_as_int(Bm.y);
                    rB = ((const uint4*)(rPI + ((size_t)ti << 8)))[j];
                    pB = ((const uint2*)(PIin + ((size_t)s << 8)))[j];
                }
                #pragma unroll 3
                for (int i = 0; i < cnt; ++i) {
                    // issue data for edge i+2 (meta Cm, fetched 2 iters ago)
                    {
                        int s = __float_as_int(Cm.x), ti = __float_as_int(Cm.y);
                        rC = ((const uint4*)(rPI + ((size_t)ti << 8)))[j];
                        pC = ((const uint2*)(PIin + ((size_t)s << 8)))[j];
                    }
                    float4 Em = M[3 * min(i + 4, lastE)];
                    float4 S1 = M[3 * i + 1];
                    float4 S2 = M[3 * i + 2];
                    // consume edge i (sh pre-scaled by fc)
                    float fr = Am.z, fc = Am.w;
                    float la = bf_lo(rA.x);
                    float va = la + fr * (bf_hi(rA.x) - la);
                    float p0 = __uint_as_float(pA.x << 16);
                    float p1 = __uint_as_float(pA.x & 0xffff0000u);
                    float p2 = __uint_as_float(pA.y << 16);
                    m0 = fmaf(p0 * va, fc, m0);
                    float lb = bf_lo(rA.y);
                    float vb = lb + fr * (bf_hi(rA.y) - lb);
                    float w1 = p1 * vb;
                    m1a[0] += w1 * S1.x;
                    m1a[1] += w1 * S1.y;
                    m1a[2] += w1 * S1.z;
                    float lc = bf_lo(rA.z);
                    float vc = lc + fr * (bf_hi(rA.z) - lc);
                    float w2 = p2 * vc;
                    m2a[0] += w2 * S1.w;
                    m2a[1] += w2 * S2.x;
                    m2a[2] += w2 * S2.y;
                    m2a[3] += w2 * S2.z;
                    m2a[4] += w2 * S2.w;
                    // rotate (renamed by unroll)
                    Am = Bm; Bm = Cm; Cm = Dm; Dm = Em;
                    rA = rB; pA = pB; rB = rC; pB = pC;
                }
            }
        }
    }

    mbuf[w][0 * PSTR + j] = m0;
    #pragma unroll
    for (int d = 0; d < 3; ++d) mbuf[w][(1 + d) * PSTR + j] = m1a[d];
    #pragma unroll
    for (int d = 0; d < 5; ++d) mbuf[w][(4 + d) * PSTR + j] = m2a[d];
    __syncthreads();
    #pragma unroll
    for (int u = 0; u < GNPB; ++u)
        for (int c = t; c < 9 * PSTR; c += 256)
            mbuf[2 * u][c] += mbuf[2 * u + 1][c];
    __syncthreads();

    // epilogue: thread t owns outputs o = t, t+256 for BOTH nodes
    float rs = res_scale[b];
    for (int o = t; o < DIMN; o += 256) {
        int row, mbase;
        if (o < M0) {
            row = o; mbase = 0;
        } else if (o < M0 + 3 * M1) {
            int q = o - M0, k = q / 3, d = q - 3 * k;
            row = 128 + k; mbase = (1 + d) * PSTR;
        } else {
            int q = o - (M0 + 3 * M1), k = q / 5, d = q - 5 * k;
            row = 192 + k; mbase = (4 + d) * PSTR;
        }
        const float4* Wv = (const float4*)(WoT + (size_t)row * 64);
        float a0 = 0, a1 = 0;
        #pragma unroll
        for (int c4 = 0; c4 < 16; ++c4) {
            float4 wv = Wv[c4];
            float4 v0 = *(const float4*)&mbuf[0][mbase + 4 * c4];
            float4 v1 = *(const float4*)&mbuf[2][mbase + 4 * c4];
            a0 += wv.x * v0.x + wv.y * v0.y + wv.z * v0.z + wv.w * v0.w;
            a1 += wv.x * v1.x + wv.y * v1.y + wv.z * v1.z + wv.w * v1.w;
        }
        a0 = x[(size_t)(n0 + 0) * DIMN + o] + rs * a0;
        a1 = x[(size_t)(n0 + 1) * DIMN + o] + rs * a1;
        if (b < NBLK - 1) {
            x[(size_t)(n0 + 0) * DIMN + o] = a0;
            x[(size_t)(n0 + 1) * DIMN + o] = a1;
            if (o < M0) {   // stash first 128 channels for the fused projection
                mbuf[1][o] = a0; mbuf[3][o] = a1;
            }
        } else {
            mbuf[1][o] = a0; mbuf[3][o] = a1;
        }
    }

    if (b < NBLK - 1) {
        // ---- fused projection for block b+1 into the OTHER PI buffer (WpT float4 rows) ----
        __syncthreads();
        for (int oo = t; oo < GNPB * 192; oo += 256) {
            int u = oo / 192, c = oo - u * 192;
            const float4* xf4 = (const float4*)mbuf[2 * u + 1];
            const float4* Wr = (const float4*)(WpTn + (size_t)c * 128);
            float acc = 0.0f;
            #pragma unroll
            for (int k4 = 0; k4 < 32; ++k4) {
                float4 wv = Wr[k4], xv = xf4[k4];
                acc += wv.x * xv.x + wv.y * xv.y + wv.z * xv.z + wv.w * xv.w;
            }
            PIout[((size_t)(n0 + u) * 64 + (c & 63)) * 4 + (c >> 6)] = f2bf(acc);
        }
        return;
    }

    // ---- final irrep norm + mask (waves 0..1 each handle one node) ----
    __syncthreads();
    if (w < GNPB) {
        const float* xf = mbuf[2 * w + 1];
        float s0 = 0, s1 = 0, s2 = 0;
        for (int c = j; c < DIMN; c += 64) {
            float v = xf[c];
            if (c < 128) s0 += v * v;
            else if (c < 320) s1 += v * v;
            else s2 += v * v;
        }
        #pragma unroll
        for (int d = 32; d > 0; d >>= 1) {
            s0 += __shfl_down(s0, d);
            s1 += __shfl_down(s1, d);
            s2 += __shfl_down(s2, d);
        }
        if (j == 0) {
            invs[w][0] = rsqrtf(s0 / (float)M0 + 1e-6f);
            invs[w][1] = rsqrtf(s1 / (float)M1 + 1e-6f);
            invs[w][2] = rsqrtf(s2 / (float)M2 + 1e-6f);
        }
    }
    __syncthreads();
    for (int o = t; o < DIMN; o += 256) {
        int cls = (o < 128) ? 0 : (o < 320) ? 1 : 2;
        #pragma unroll
        for (int u = 0; u < GNPB; ++u) {
            float fm = mask[n0 + u];
            out[(size_t)(n0 + u) * DIMN + o] = mbuf[2 * u + 1][o] * invs[u][cls] * fm;
        }
    }
}

extern "C" void kernel_launch(void* const* d_in, const int* in_sizes, int n_in,
                              void* d_out, int out_size, void* d_ws, size_t ws_size,
                              hipStream_t stream) {
    const int*   z    = (const int*)d_in[0];
    const float* mask = (const float*)d_in[1];
    const int*   esrc = (const int*)d_in[2];
    const int*   edst = (const int*)d_in[3];
    const float* ew   = (const float*)d_in[4];
    const float* ev   = (const float*)d_in[5];
    const float* zemb = (const float*)d_in[6];
    const float* Win  = (const float*)d_in[7];
    const float* Wp   = (const float*)d_in[8];
    const float* rW1  = (const float*)d_in[9];
    const float* rb1  = (const float*)d_in[10];
    const float* rW2  = (const float*)d_in[11];
    const float* rb2  = (const float*)d_in[12];
    const float* Wo0  = (const float*)d_in[13];
    const float* Wo1  = (const float*)d_in[14];
    const float* Wo2  = (const float*)d_in[15];
    const float* res  = (const float*)d_in[16];

    const int BN = in_sizes[0];      // 4096
    const int E  = in_sizes[2];      // 131072

    // ---- workspace carve (16B-aligned pieces) ----
    char* w = (char*)d_ws;
    float* x    = (float*)w;  w += (size_t)BN * DIMN * 4;            // 7.86 MB
    u16*   PIa  = (u16*)w;    w += (size_t)BN * 256 * 2;             // 2.10 MB
    u16*   PIb  = (u16*)w;    w += (size_t)BN * 256 * 2;             // 2.10 MB
    u32*   rPI  = (u32*)w;    w += (size_t)NBLK * NT * 256 * 4;      // 1.57 MB
    ERec*  rec  = (ERec*)w;   w += (size_t)E * sizeof(ERec);         // 6.29 MB
    float* WoT  = (float*)w;  w += (size_t)NBLK * WROWS * 64 * 4;    // 172 KB
    float* WpT  = (float*)w;  w += (size_t)NBLK * 192 * 128 * 4;     // 295 KB
    int* counts = (int*)w;   w += (size_t)BN * 4;
    int* offs   = (int*)w;   w += (size_t)(BN + 4) * 4;
    int* cursor = (int*)w;   w += (size_t)BN * 4;

    k_zero<<<(BN + 255) / 256, 256, 0, stream>>>(counts, BN);
    k_count<<<(E + 255) / 256, 256, 0, stream>>>(edst, counts, E);
    k_scan<<<1, 1024, 0, stream>>>(counts, offs, cursor, BN);
    k_build<<<(E + 255) / 256, 256, 0, stream>>>(ew, ev, esrc, edst, cursor, rec, E);
    {
        int tail = NBLK * WROWS * 64 + NBLK * 192 * 128;
        int tb = (tail + 255) / 256;
        k_rtab<<<RTB + tb, 256, 0, stream>>>(rW1, rb1, rW2, rb2, rPI,
                                             Wo0, Wo1, Wo2, WoT, Wp, WpT);
    }
    k_proj0<<<BN / NNP0, 192, 0, stream>>>(z, mask, zemb, Win, Wp, x, PIa);

    u16* pibuf[2] = {PIa, PIb};
    for (int b = 0; b < NBLK; ++b) {
        const float* WpTn = WpT + (size_t)(b + 1 < NBLK ? b + 1 : 0) * 192 * 128;
        k_gather<<<BN / GNPB, 256, 0, stream>>>(pibuf[b & 1], pibuf[(b + 1) & 1],
                                                rPI + (size_t)b * NT * 256,
                                                rec, offs,
                                                WoT + (size_t)b * WROWS * 64,
                                                WpTn, res, b, x, mask, (float*)d_out);
    }
}

// Round 23
// 188.098 us; speedup vs baseline: 1.3014x; 1.3014x over previous
//
#include <hip/hip_runtime.h>
#include <math.h>

#define M0 128
#define M1 64
#define M2 32
#define DIMN 480      // 128 + 3*64 + 5*32
#define MSGC 64
#define NBLK 3
#define RBFD 32
#define NT 512        // r-table resolution (rPI = 0.5 MB/b -> L2-resident)
#define TCHUNK 16     // t-values per k_rtab block (96 table blocks)
#define NNP0 4        // nodes per k_proj0 block
#define GNPB 4        // nodes per k_gather block (2 waves each, 512 threads)
#define PSTR 68       // mbuf plane stride (floats)
#define WROWS 224     // WoT rows: 128 + 64 + 32
#define CH 21         // edges per wave-private staged chunk (63 float4 slots)
#define FCUT 5.0f

typedef unsigned int   u32;
typedef unsigned short u16;

__device__ __forceinline__ u16 f2bf(float f) {
    u32 u = __float_as_uint(f);
    u32 r = (u + 0x7fffu + ((u >> 16) & 1u)) >> 16;
    return (u16)r;
}
__device__ __forceinline__ float bf_lo(u32 v) { return __uint_as_float(v << 16); }
__device__ __forceinline__ float bf_hi(u32 v) { return __uint_as_float(v & 0xffff0000u); }

// 48-byte dst-sorted edge record: [src,ti,fr,fc][shf1..4][shf5..8] (sh pre-scaled by fcut)
struct __align__(16) ERec {
    int   src;
    int   ti;
    float fr;
    float fc;
    float sh[8];
};

// ---------- zero counts ----------
__global__ void k_zero(int* __restrict__ p, int n) {
    int i = blockIdx.x * blockDim.x + threadIdx.x;
    if (i < n) p[i] = 0;
}

// ---------- pass 1: count edges per dst ----------
__global__ void k_count(const int* __restrict__ dst, int* __restrict__ counts, int E) {
    int e = blockIdx.x * blockDim.x + threadIdx.x;
    if (e >= E) return;
    atomicAdd(&counts[dst[e]], 1);
}

// ---------- exclusive scan, 4 elems/thread + Hillis-Steele on 1024 totals ----------
__global__ __launch_bounds__(1024) void k_scan(const int* __restrict__ counts,
                                               int* __restrict__ offs,
                                               int* __restrict__ cursor, int n) {
    __shared__ int ws[1024];
    int t = threadIdx.x;                 // n == 4096, 4 per thread
    int4 v = ((const int4*)counts)[t];
    int s0 = v.x, s1 = s0 + v.y, s2 = s1 + v.z, s3 = s2 + v.w;
    ws[t] = s3;
    __syncthreads();
    for (int d = 1; d < 1024; d <<= 1) {
        int val = (t >= d) ? ws[t - d] : 0;
        __syncthreads();
        ws[t] += val;
        __syncthreads();
    }
    int excl = (t == 0) ? 0 : ws[t - 1];
    int4 o;
    o.x = excl; o.y = excl + s0; o.z = excl + s1; o.w = excl + s2;
    ((int4*)offs)[t] = o;
    ((int4*)cursor)[t] = o;
    if (t == 1023) offs[n] = excl + s3;
}

// ---------- pass 2: edge features scattered into dst order (sh pre-scaled by fcut) ----------
__global__ void k_build(const float* __restrict__ ew, const float* __restrict__ ev,
                        const int* __restrict__ src, const int* __restrict__ dst,
                        int* __restrict__ cursor, ERec* __restrict__ rec, int E) {
    int e = blockIdx.x * blockDim.x + threadIdx.x;
    if (e >= E) return;
    float len = ew[e];
    float inv = 1.0f / fmaxf(len, 1e-8f);
    float x = ev[e * 3 + 0] * inv;
    float y = ev[e * 3 + 1] * inv;
    float z = ev[e * 3 + 2] * inv;
    const float s3 = 1.7320508075688772f, s5 = 2.23606797749979f, s15 = 3.872983346207417f;
    ERec r;
    r.src = src[e];
    float u = fminf(len, FCUT) * ((float)(NT - 1) / FCUT);
    int ti = (int)u;
    ti = min(ti, NT - 2);
    r.ti = ti;
    r.fr = u - (float)ti;
    float t = fminf(len / FCUT, 1.0f);
    float fc = 0.5f * (cosf(3.14159265358979323846f * t) + 1.0f);
    r.fc = fc;
    r.sh[0] = s3 * x * fc;
    r.sh[1] = s3 * y * fc;
    r.sh[2] = s3 * z * fc;
    r.sh[3] = s15 * x * y * fc;
    r.sh[4] = s15 * y * z * fc;
    r.sh[5] = 0.5f * s5 * (3.0f * z * z - 1.0f) * fc;
    r.sh[6] = s15 * x * z * fc;
    r.sh[7] = 0.5f * s15 * (x * x - y * y) * fc;
    int p = atomicAdd(&cursor[dst[e]], 1);
    rec[p] = r;
}

// ---------- r-table direct-pack + Wo transpose (one launch) ----------
#define RTB (NBLK * (NT / TCHUNK))
__global__ __launch_bounds__(256) void k_rtab(const float* __restrict__ rW1,
                                              const float* __restrict__ rb1,
                                              const float* __restrict__ rW2,
                                              const float* __restrict__ rb2,
                                              u32* __restrict__ rPI,
                                              const float* __restrict__ Wo0,
                                              const float* __restrict__ Wo1,
                                              const float* __restrict__ Wo2,
                                              float* __restrict__ WoT) {
    int blk = blockIdx.x;
    int tid = threadIdx.x;
    if (blk >= RTB) {
        int idx = (blk - RTB) * 256 + tid;
        const int wtot = NBLK * WROWS * 64;
        if (idx >= wtot) return;
        int b = idx / (WROWS * 64);
        int rem = idx - b * (WROWS * 64);
        int row = rem >> 6, c = rem & 63;
        float v;
        if (row < 128)      v = Wo0[(size_t)b * MSGC * M0 + c * M0 + row];
        else if (row < 192) v = Wo1[(size_t)b * MSGC * M1 + c * M1 + (row - 128)];
        else                v = Wo2[(size_t)b * MSGC * M2 + c * M2 + (row - 192)];
        WoT[idx] = v;
        return;
    }
    int b = blk / (NT / TCHUNK);
    int t0 = (blk % (NT / TCHUNK)) * TCHUNK;
    __shared__ float rbf_s[TCHUNK + 1][RBFD];
    __shared__ float hh_s[64][TCHUNK + 1];

    const float wdt = FCUT / (float)(RBFD - 1);
    for (int idx = tid; idx < (TCHUNK + 1) * RBFD; idx += 256) {
        int tt = idx >> 5, k = idx & 31;
        int te = min(t0 + tt, NT - 1);
        float len = (float)te * (FCUT / (float)(NT - 1));
        float d0 = (len - (float)k * wdt) / wdt;
        rbf_s[tt][k] = expf(-0.5f * d0 * d0);
    }
    __syncthreads();
    const float* W1 = rW1 + b * RBFD * 64;
    for (int idx = tid; idx < (TCHUNK + 1) * 64; idx += 256) {
        int tt = idx / 64, jj = idx & 63;
        float a = rb1[b * 64 + jj];
        #pragma unroll 8
        for (int k = 0; k < RBFD; ++k) a += rbf_s[tt][k] * W1[k * 64 + jj];
        hh_s[jj][tt] = a / (1.0f + expf(-a));
    }
    __syncthreads();
    if (tid < 192) {
        int c = tid;
        const float* W2 = rW2 + b * 64 * 192;
        float w2r[64];
        #pragma unroll
        for (int k = 0; k < 64; ++k) w2r[k] = W2[k * 192 + c];
        float b2 = rb2[b * 192 + c];
        int lane = c & 63, q = c >> 6;
        u32* out = rPI + ((size_t)b * NT * 64) * 4;
        float prev = 0.0f;
        for (int tt = 0; tt <= TCHUNK; ++tt) {
            float acc = b2;
            #pragma unroll
            for (int k = 0; k < 64; ++k) acc += hh_s[k][tt] * w2r[k];
            if (tt > 0) {
                int t = t0 + tt - 1;
                out[((size_t)t * 64 + lane) * 4 + q] =
                    (u32)f2bf(prev) | ((u32)f2bf(acc) << 16);
            }
            prev = acc;
        }
    }
}

// ---------- fused x-init + b=0 projection (4 nodes/block, 1024 blocks) ----------
__global__ __launch_bounds__(192) void k_proj0(const int* __restrict__ z,
                                               const float* __restrict__ mask,
                                               const float* __restrict__ zemb,
                                               const float* __restrict__ Win,
                                               const float* __restrict__ Wp,
                                               float* __restrict__ x,
                                               u16* __restrict__ PI) {
    int n0 = blockIdx.x * NNP0;
    int j = threadIdx.x;
    __shared__ float zf[NNP0][M0];
    __shared__ float xs[NNP0][M0];
    for (int idx = j; idx < NNP0 * M0; idx += 192) {
        int n = idx >> 7, c = idx & 127;
        zf[n][c] = zemb[z[n0 + n] * M0 + c];
    }
    __syncthreads();
    for (int idx = j; idx < NNP0 * M0; idx += 192) {
        int n = idx >> 7, c = idx & 127;
        float acc = 0.0f;
        for (int k = 0; k < M0; ++k) acc += zf[n][k] * Win[k * M0 + c];
        acc *= mask[n0 + n];
        xs[n][c] = acc;
        x[(size_t)(n0 + n) * DIMN + c] = acc;
    }
    for (int idx = j; idx < NNP0 * (DIMN - M0); idx += 192) {
        int n = idx / (DIMN - M0), c = idx - n * (DIMN - M0);
        x[(size_t)(n0 + n) * DIMN + M0 + c] = 0.0f;
    }
    __syncthreads();
    float acc[NNP0];
    #pragma unroll
    for (int u = 0; u < NNP0; ++u) acc[u] = 0.0f;
    for (int k = 0; k < M0; ++k) {
        float wv = Wp[k * 192 + j];
        #pragma unroll
        for (int u = 0; u < NNP0; ++u) acc[u] += xs[u][k] * wv;
    }
    int lane = j & 63, q = j >> 6;
    #pragma unroll
    for (int u = 0; u < NNP0; ++u)
        PI[((size_t)(n0 + u) * 64 + lane) * 4 + q] = f2bf(acc[u]);
}

// ---------- fused gather + Wo transform + next-block projection (+ final norm) ----------
// 512 threads = 8 waves; 4 nodes/block, 2 waves/node (CONTIGUOUS edge split).
// Each wave bulk-stages its own edge metas into wave-private LDS (coalesced,
// double-buffered, no barrier), then runs a 2-deep register data pipeline
// whose addresses come from cheap LDS broadcast reads.
__global__ __launch_bounds__(512, 6) void k_gather(const u16* __restrict__ PIin,
                                                   u16* __restrict__ PIout,
                                                   const u32* __restrict__ rPI,
                                                   const ERec* __restrict__ rec,
                                                   const int* __restrict__ offs,
                                                   const float* __restrict__ WoT,
                                                   const float* __restrict__ WpNext,
                                                   const float* __restrict__ res_scale, int b,
                                                   float* __restrict__ x,
                                                   const float* __restrict__ mask,
                                                   float* __restrict__ out) {
    int t = threadIdx.x;
    int w = t >> 6;          // wave 0..7
    int j = t & 63;
    int local = w >> 1;      // node within block 0..3
    int par = w & 1;         // wave half within node
    int n0 = blockIdx.x * GNPB;
    int n = n0 + local;
    int e0 = offs[n], e1 = offs[n + 1];

    float m0 = 0.0f;
    float m1a[3] = {0, 0, 0};
    float m2a[5] = {0, 0, 0, 0, 0};

    __shared__ float4 smeta[8][2][CH * 3];   // wave-private staging, double-buffered
    __shared__ float mbuf[8][9 * PSTR];      // odd slices reused as x-stash after reduce
    __shared__ float invs[GNPB][3];

    {
        int half = (e1 - e0 + 1) >> 1;
        int a    = e0 + par * half;
        int bnd  = par ? e1 : (e0 + half);
        int len  = bnd - a;
        if (len > 0) {
            const float4* RP = (const float4*)rec;
            // stage chunk 0
            {
                int c0 = min(CH, len);
                if (j < c0 * 3) smeta[w][0][j] = RP[(size_t)3 * a + j];
            }
            int buf = 0;
            for (int done = 0; done < len; done += CH, buf ^= 1) {
                int cnt = min(CH, len - done);
                // stage next chunk into other buffer (loads overlap processing)
                {
                    int nd = done + CH;
                    int ncnt = min(CH, len - nd);
                    if (j < ncnt * 3) smeta[w][buf ^ 1][j] = RP[(size_t)3 * (a + nd) + j];
                }
                const float4* M = smeta[w][buf];
                int lastE = cnt - 1;
                // meta queue: Am=edge0, Bm=1, Cm=2, Dm=3 (clamped)
                float4 Am = M[0];
                float4 Bm = M[3 * min(1, lastE)];
                float4 Cm = M[3 * min(2, lastE)];
                float4 Dm = M[3 * min(3, lastE)];
                // data pipeline 2-deep
                uint4 rA, rB, rC; uint2 pA, pB, pC;
                {
                    int s = __float_as_int(Am.x), ti = __float_as_int(Am.y);
                    rA = ((const uint4*)(rPI + ((size_t)ti << 8)))[j];
                    pA = ((const uint2*)(PIin + ((size_t)s << 8)))[j];
                }
                {
                    int s = __float_as_int(Bm.x), ti = __float_as_int(Bm.y);
                    rB = ((const uint4*)(rPI + ((size_t)ti << 8)))[j];
                    pB = ((const uint2*)(PIin + ((size_t)s << 8)))[j];
                }
                #pragma unroll 3
                for (int i = 0; i < cnt; ++i) {
                    // issue data for edge i+2 (meta Cm, fetched 2 iters ago)
                    {
                        int s = __float_as_int(Cm.x), ti = __float_as_int(Cm.y);
                        rC = ((const uint4*)(rPI + ((size_t)ti << 8)))[j];
                        pC = ((const uint2*)(PIin + ((size_t)s << 8)))[j];
                    }
                    // fetch meta for edge i+4 (clamped; LDS broadcast)
                    float4 Em = M[3 * min(i + 4, lastE)];
                    // sh for edge i (LDS broadcast reads)
                    float4 S1 = M[3 * i + 1];
                    float4 S2 = M[3 * i + 2];
                    // consume edge i (sh pre-scaled by fc)
                    float fr = Am.z, fc = Am.w;
                    float la = bf_lo(rA.x);
                    float va = la + fr * (bf_hi(rA.x) - la);
                    float p0 = __uint_as_float(pA.x << 16);
                    float p1 = __uint_as_float(pA.x & 0xffff0000u);
                    float p2 = __uint_as_float(pA.y << 16);
                    m0 = fmaf(p0 * va, fc, m0);
                    float lb = bf_lo(rA.y);
                    float vb = lb + fr * (bf_hi(rA.y) - lb);
                    float w1 = p1 * vb;
                    m1a[0] += w1 * S1.x;
                    m1a[1] += w1 * S1.y;
                    m1a[2] += w1 * S1.z;
                    float lc = bf_lo(rA.z);
                    float vc = lc + fr * (bf_hi(rA.z) - lc);
                    float w2 = p2 * vc;
                    m2a[0] += w2 * S1.w;
                    m2a[1] += w2 * S2.x;
                    m2a[2] += w2 * S2.y;
                    m2a[3] += w2 * S2.z;
                    m2a[4] += w2 * S2.w;
                    // rotate (renamed by unroll)
                    Am = Bm; Bm = Cm; Cm = Dm; Dm = Em;
                    rA = rB; pA = pB; rB = rC; pB = pC;
                }
            }
        }
    }

    mbuf[w][0 * PSTR + j] = m0;
    #pragma unroll
    for (int d = 0; d < 3; ++d) mbuf[w][(1 + d) * PSTR + j] = m1a[d];
    #pragma unroll
    for (int d = 0; d < 5; ++d) mbuf[w][(4 + d) * PSTR + j] = m2a[d];
    __syncthreads();
    // pair-reduce the two waves of each node into the even slice
    #pragma unroll
    for (int u = 0; u < GNPB; ++u)
        for (int c = t; c < 9 * PSTR; c += 512)
            mbuf[2 * u][c] += mbuf[2 * u + 1][c];
    __syncthreads();

    // epilogue: thread t owns output o = t for ALL 4 nodes
    float rs = res_scale[b];
    int o = t;
    if (o < DIMN) {
        int row, mbase;
        if (o < M0) {
            row = o; mbase = 0;
        } else if (o < M0 + 3 * M1) {
            int q = o - M0, k = q / 3, d = q - 3 * k;
            row = 128 + k; mbase = (1 + d) * PSTR;
        } else {
            int q = o - (M0 + 3 * M1), k = q / 5, d = q - 5 * k;
            row = 192 + k; mbase = (4 + d) * PSTR;
        }
        const float4* Wv = (const float4*)(WoT + (size_t)row * 64);
        float a0 = 0, a1 = 0, a2 = 0, a3 = 0;
        #pragma unroll
        for (int c4 = 0; c4 < 16; ++c4) {
            float4 wv = Wv[c4];
            float4 v0 = *(const float4*)&mbuf[0][mbase + 4 * c4];
            float4 v1 = *(const float4*)&mbuf[2][mbase + 4 * c4];
            float4 v2 = *(const float4*)&mbuf[4][mbase + 4 * c4];
            float4 v3 = *(const float4*)&mbuf[6][mbase + 4 * c4];
            a0 += wv.x * v0.x + wv.y * v0.y + wv.z * v0.z + wv.w * v0.w;
            a1 += wv.x * v1.x + wv.y * v1.y + wv.z * v1.z + wv.w * v1.w;
            a2 += wv.x * v2.x + wv.y * v2.y + wv.z * v2.z + wv.w * v2.w;
            a3 += wv.x * v3.x + wv.y * v3.y + wv.z * v3.z + wv.w * v3.w;
        }
        a0 = x[(size_t)(n0 + 0) * DIMN + o] + rs * a0;
        a1 = x[(size_t)(n0 + 1) * DIMN + o] + rs * a1;
        a2 = x[(size_t)(n0 + 2) * DIMN + o] + rs * a2;
        a3 = x[(size_t)(n0 + 3) * DIMN + o] + rs * a3;
        if (b < NBLK - 1) {
            x[(size_t)(n0 + 0) * DIMN + o] = a0;
            x[(size_t)(n0 + 1) * DIMN + o] = a1;
            x[(size_t)(n0 + 2) * DIMN + o] = a2;
            x[(size_t)(n0 + 3) * DIMN + o] = a3;
            if (o < M0) {   // stash first 128 channels for the fused projection
                mbuf[1][o] = a0; mbuf[3][o] = a1; mbuf[5][o] = a2; mbuf[7][o] = a3;
            }
        } else {
            mbuf[1][o] = a0; mbuf[3][o] = a1; mbuf[5][o] = a2; mbuf[7][o] = a3;
        }
    }

    if (b < NBLK - 1) {
        // ---- fused projection for block b+1 into the OTHER PI buffer ----
        __syncthreads();
        for (int oo = t; oo < GNPB * 192; oo += 512) {
            int u = oo / 192, c = oo - u * 192;
            const float* xf = mbuf[2 * u + 1];
            float acc = 0.0f;
            #pragma unroll 8
            for (int k = 0; k < M0; ++k) acc += xf[k] * WpNext[k * 192 + c];
            PIout[((size_t)(n0 + u) * 64 + (c & 63)) * 4 + (c >> 6)] = f2bf(acc);
        }
        return;
    }

    // ---- final irrep norm + mask (waves 0..3 each handle one node) ----
    __syncthreads();
    if (w < GNPB) {
        const float* xf = mbuf[2 * w + 1];
        float s0 = 0, s1 = 0, s2 = 0;
        for (int c = j; c < DIMN; c += 64) {
            float v = xf[c];
            if (c < 128) s0 += v * v;
            else if (c < 320) s1 += v * v;
            else s2 += v * v;
        }
        #pragma unroll
        for (int d = 32; d > 0; d >>= 1) {
            s0 += __shfl_down(s0, d);
            s1 += __shfl_down(s1, d);
            s2 += __shfl_down(s2, d);
        }
        if (j == 0) {
            invs[w][0] = rsqrtf(s0 / (float)M0 + 1e-6f);
            invs[w][1] = rsqrtf(s1 / (float)M1 + 1e-6f);
            invs[w][2] = rsqrtf(s2 / (float)M2 + 1e-6f);
        }
    }
    __syncthreads();
    int o2 = t;
    if (o2 < DIMN) {
        int cls = (o2 < 128) ? 0 : (o2 < 320) ? 1 : 2;
        #pragma unroll
        for (int u = 0; u < GNPB; ++u) {
            float fm = mask[n0 + u];
            out[(size_t)(n0 + u) * DIMN + o2] = mbuf[2 * u + 1][o2] * invs[u][cls] * fm;
        }
    }
}

extern "C" void kernel_launch(void* const* d_in, const int* in_sizes, int n_in,
                              void* d_out, int out_size, void* d_ws, size_t ws_size,
                              hipStream_t stream) {
    const int*   z    = (const int*)d_in[0];
    const float* mask = (const float*)d_in[1];
    const int*   esrc = (const int*)d_in[2];
    const int*   edst = (const int*)d_in[3];
    const float* ew   = (const float*)d_in[4];
    const float* ev   = (const float*)d_in[5];
    const float* zemb = (const float*)d_in[6];
    const float* Win  = (const float*)d_in[7];
    const float* Wp   = (const float*)d_in[8];
    const float* rW1  = (const float*)d_in[9];
    const float* rb1  = (const float*)d_in[10];
    const float* rW2  = (const float*)d_in[11];
    const float* rb2  = (const float*)d_in[12];
    const float* Wo0  = (const float*)d_in[13];
    const float* Wo1  = (const float*)d_in[14];
    const float* Wo2  = (const float*)d_in[15];
    const float* res  = (const float*)d_in[16];

    const int BN = in_sizes[0];      // 4096
    const int E  = in_sizes[2];      // 131072

    // ---- workspace carve (16B-aligned pieces) ----
    char* w = (char*)d_ws;
    float* x    = (float*)w;  w += (size_t)BN * DIMN * 4;            // 7.86 MB
    u16*   PIa  = (u16*)w;    w += (size_t)BN * 256 * 2;             // 2.10 MB
    u16*   PIb  = (u16*)w;    w += (size_t)BN * 256 * 2;             // 2.10 MB
    u32*   rPI  = (u32*)w;    w += (size_t)NBLK * NT * 256 * 4;      // 1.57 MB
    ERec*  rec  = (ERec*)w;   w += (size_t)E * sizeof(ERec);         // 6.29 MB
    float* WoT  = (float*)w;  w += (size_t)NBLK * WROWS * 64 * 4;    // 172 KB
    int* counts = (int*)w;   w += (size_t)BN * 4;
    int* offs   = (int*)w;   w += (size_t)(BN + 4) * 4;
    int* cursor = (int*)w;   w += (size_t)BN * 4;

    k_zero<<<(BN + 255) / 256, 256, 0, stream>>>(counts, BN);
    k_count<<<(E + 255) / 256, 256, 0, stream>>>(edst, counts, E);
    k_scan<<<1, 1024, 0, stream>>>(counts, offs, cursor, BN);
    k_build<<<(E + 255) / 256, 256, 0, stream>>>(ew, ev, esrc, edst, cursor, rec, E);
    {
        int wotb = (NBLK * WROWS * 64 + 255) / 256;
        k_rtab<<<RTB + wotb, 256, 0, stream>>>(rW1, rb1, rW2, rb2, rPI,
                                               Wo0, Wo1, Wo2, WoT);
    }
    k_proj0<<<BN / NNP0, 192, 0, stream>>>(z, mask, zemb, Win, Wp, x, PIa);

    u16* pibuf[2] = {PIa, PIb};
    for (int b = 0; b < NBLK; ++b) {
        const float* WpNext = Wp + (size_t)(b + 1 < NBLK ? b + 1 : 0) * M0 * 192;
        k_gather<<<BN / GNPB, 512, 0, stream>>>(pibuf[b & 1], pibuf[(b + 1) & 1],
                                                rPI + (size_t)b * NT * 256,
                                                rec, offs,
                                                WoT + (size_t)b * WROWS * 64,
                                                WpNext, res, b, x, mask, (float*)d_out);
    }
}